// Round 16
// baseline (109.709 us; speedup 1.0000x reference)
//
#include <hip/hip_runtime.h>
#include <math.h>

// Problem constants (fixed by reference)
#define S_LEN   2048
#define HDIM    1024
#define NHEADS  16
#define DHEAD   64
#define BATCH   2
#define MROWS   (BATCH * S_LEN)   // 4096
#define STRIDE  4
#define LOCAL   8
#define NSTRIDED (S_LEN / STRIDE)  // 512

typedef __attribute__((ext_vector_type(8))) _Float16 f16x8;  // 8 fp16 (4 VGPRs)
typedef __attribute__((ext_vector_type(4))) float f32x4;

// ---- fp32 -> fp16 (RN) bit helpers -----------------------------------------
__device__ __forceinline__ unsigned short f16b(float x) {
    _Float16 h = (_Float16)x;
    unsigned short u;
    __builtin_memcpy(&u, &h, 2);
    return u;
}
__device__ __forceinline__ unsigned pack2_f16(float a, float b) {
    return (unsigned)f16b(a) | ((unsigned)f16b(b) << 16);
}

// ---- async global->LDS, 16B per lane (dest = wave base + lane*16) ----------
__device__ __forceinline__ void gll16(const void* g, void* l) {
    __builtin_amdgcn_global_load_lds(
        (const __attribute__((address_space(1))) void*)g,
        (__attribute__((address_space(3))) void*)l, 16, 0, 0);
}

// ---- T4 sync helpers (attention kernel only) -------------------------------
#define WAIT_BARRIER(N)                                             \
    do {                                                            \
        asm volatile("s_waitcnt vmcnt(" #N ")" ::: "memory");       \
        __builtin_amdgcn_s_barrier();                               \
        __builtin_amdgcn_sched_barrier(0);                          \
    } while (0)
#define READ_DONE_BARRIER()                                         \
    do {                                                            \
        __builtin_amdgcn_s_barrier();                               \
        __builtin_amdgcn_sched_barrier(0);                          \
    } while (0)

// ---------------------------------------------------------------------------
// Prep 1: x fp32 -> fp16 bits, 4 elems/thread.
// ---------------------------------------------------------------------------
__global__ __launch_bounds__(256)
void xcvt(const float* __restrict__ src, unsigned short* __restrict__ dst, int n4)
{
    const int i = blockIdx.x * 256 + threadIdx.x;
    if (i >= n4) return;
    const float4 v = reinterpret_cast<const float4*>(src)[i];
    reinterpret_cast<ushort4*>(dst)[i] =
        make_ushort4(f16b(v.x), f16b(v.y), f16b(v.z), f16b(v.w));
}

// ---------------------------------------------------------------------------
// Prep 2: weights [K][N] fp32 -> transposed fp16 [N][K]; z picks the weight.
// ---------------------------------------------------------------------------
__global__ __launch_bounds__(256)
void wcvt(const float* __restrict__ W0, const float* __restrict__ W1,
          const float* __restrict__ W2, const float* __restrict__ W3,
          unsigned short* __restrict__ dst)
{
    __shared__ unsigned short tile[32][33];
    const int z = blockIdx.z;
    const float* __restrict__ W = (z == 0) ? W0 : (z == 1) ? W1 : (z == 2) ? W2 : W3;
    unsigned short* __restrict__ out = dst + (size_t)z * HDIM * HDIM;
    const int t  = threadIdx.x;
    const int kb = blockIdx.x * 32;
    const int nb = blockIdx.y * 32;
    {
        const int row = t >> 3;
        const int c4  = (t & 7) * 4;
        const float4 v = *reinterpret_cast<const float4*>(
            &W[(size_t)(kb + row) * HDIM + nb + c4]);
        tile[row][c4 + 0] = f16b(v.x);
        tile[row][c4 + 1] = f16b(v.y);
        tile[row][c4 + 2] = f16b(v.z);
        tile[row][c4 + 3] = f16b(v.w);
    }
    __syncthreads();
    {
        const int n  = t >> 3;
        const int k4 = (t & 7) * 4;
        *reinterpret_cast<ushort4*>(&out[(size_t)(nb + n) * HDIM + kb + k4]) =
            make_ushort4(tile[k4][n], tile[k4+1][n], tile[k4+2][n], tile[k4+3][n]);
    }
}

// ---------------------------------------------------------------------------
// QKV fp16 MFMA GEMM — the m97 structure: 128x128 tile, BK=64,
// SINGLE-buffered 32 KB LDS, plain 2-barrier __syncthreads loop.
// Pipelining comes from CROSS-BLOCK TLP: grid (8,32,3)=768 = 3 blocks/CU
// co-resident (LDS cap 5, wave cap 8) — m114/m132: this residency is what
// hides the per-step drain; 64KB dbuf (rounds 13-15) capped it at 1-2 and
// pinned us at ~508 TF (m132's exact number).
// Epilogue (z): 0 -> Q scaled; 1 -> K + Kp; 2 -> Vt + Vpt.
// ---------------------------------------------------------------------------
__global__ __launch_bounds__(256)
void gemm_qkv(const unsigned short* __restrict__ A,
              const unsigned short* __restrict__ Wbase,
              const float* __restrict__ sig_ptr,
              unsigned short* __restrict__ Qf, unsigned short* __restrict__ Kf,
              unsigned short* __restrict__ Kp, unsigned short* __restrict__ Vt,
              unsigned short* __restrict__ Vpt)
{
    __shared__ unsigned short As[128 * 64];   // 16 KB
    __shared__ unsigned short Bs[128 * 64];   // 16 KB

    const int z = blockIdx.z;
    const unsigned short* __restrict__ WT = Wbase + (size_t)z * HDIM * HDIM;

    const int tid  = threadIdx.x;
    const int lane = tid & 63;
    const int w    = tid >> 6;
    const int wr   = w >> 1;      // wave row: 64 rows
    const int wc   = w & 1;       // wave col: 64 cols
    const int row_base = blockIdx.y * 128;
    const int col_base = blockIdx.x * 128;

    f32x4 acc[4][4] = {};

    // stage one 128x64 A-tile + 128x64 B-tile; LDS dest linear in chunk id
    // (gll constraint), global source pre-swizzled for conflict-free reads.
    auto stage = [&](int k0) {
#pragma unroll
        for (int r = 0; r < 4; ++r) {
            const int c    = tid + r * 256;      // chunk 0..1023
            const int row  = c >> 3;             // tile row 0..127
            const int c7   = c & 7;              // 16B chunk in 128B row
            const int goff = ((c7 * 16) ^ ((row & 7) << 4)) >> 1;  // f16 elems
            gll16(A  + (size_t)(row_base + row) * HDIM + k0 + goff, &As[c * 8]);
            gll16(WT + (size_t)(col_base + row) * HDIM + k0 + goff, &Bs[c * 8]);
        }
    };

    auto compute = [&]() {
#pragma unroll
        for (int kk = 0; kk < 2; ++kk) {
            const int sofs = (kk * 64 + ((lane >> 4) << 4)) ^ ((lane & 7) << 4);
            f16x8 af[4], bfr[4];
#pragma unroll
            for (int mi = 0; mi < 4; ++mi) {
                const int row = wr * 64 + mi * 16 + (lane & 15);
                af[mi] = *reinterpret_cast<const f16x8*>(
                    reinterpret_cast<const char*>(&As[row * 64]) + sofs);
            }
#pragma unroll
            for (int ni = 0; ni < 4; ++ni) {
                const int row = wc * 64 + ni * 16 + (lane & 15);
                bfr[ni] = *reinterpret_cast<const f16x8*>(
                    reinterpret_cast<const char*>(&Bs[row * 64]) + sofs);
            }
#pragma unroll
            for (int mi = 0; mi < 4; ++mi)
#pragma unroll
                for (int ni = 0; ni < 4; ++ni)
                    acc[mi][ni] = __builtin_amdgcn_mfma_f32_16x16x32_f16(
                        af[mi], bfr[ni], acc[mi][ni], 0, 0, 0);
        }
    };

    // ---- m97 2-barrier loop: stage -> sync -> compute -> sync ----
#pragma unroll 1
    for (int kt = 0; kt < 16; ++kt) {
        stage(kt * 64);
        __syncthreads();          // drains gll loads; tile ready
        compute();
        __syncthreads();          // all reads done; LDS free for next stage
    }

    // ---- attention-layout epilogue ----
    float scale = 1.0f;
    if (z == 0) {
        const float u = *sig_ptr;
        scale = (1.0f / (1.0f + __expf(-u))) * 0.125f;  // sigmoid(phi)/sqrt(D)
    }
#pragma unroll
    for (int mi = 0; mi < 4; ++mi) {
#pragma unroll
        for (int ni = 0; ni < 4; ++ni) {
            const int gr0 = row_base + wr * 64 + mi * 16 + ((lane >> 4) << 2);
            const int gc  = col_base + wc * 64 + ni * 16 + (lane & 15);
            const int h = gc >> 6, d = gc & 63;
            const int bb = gr0 >> 11;
            const int s0 = gr0 & (S_LEN - 1);       // multiple of 4
            const size_t bh = (size_t)(bb * NHEADS + h);
            if (z == 0) {
#pragma unroll
                for (int r = 0; r < 4; ++r)
                    Qf[(bh * S_LEN + s0 + r) * DHEAD + d] =
                        f16b(acc[mi][ni][r] * scale);
            } else if (z == 1) {
#pragma unroll
                for (int r = 0; r < 4; ++r)
                    Kf[(bh * S_LEN + s0 + r) * DHEAD + d] = f16b(acc[mi][ni][r]);
                Kp[(bh * NSTRIDED + (s0 >> 2)) * DHEAD + d] = f16b(acc[mi][ni][0]);
            } else {
                ushort4 pv = make_ushort4(f16b(acc[mi][ni][0]), f16b(acc[mi][ni][1]),
                                          f16b(acc[mi][ni][2]), f16b(acc[mi][ni][3]));
                *reinterpret_cast<ushort4*>(&Vt[(bh * DHEAD + d) * S_LEN + s0]) = pv;
                Vpt[(bh * DHEAD + d) * NSTRIDED + (s0 >> 2)] = pv.x;
            }
        }
    }
}

// ---------------------------------------------------------------------------
// O-projection fp16 MFMA GEMM, 128(M)x64(N) tile, SINGLE-buffered 24 KB LDS,
// plain 2-barrier loop. Grid (16,32) = 512 blocks = 2 dispatched/CU with
// high residency headroom (LDS cap 6, wave cap 8).
// ---------------------------------------------------------------------------
__global__ __launch_bounds__(256)
void gemm_out(const unsigned short* __restrict__ A,
              const unsigned short* __restrict__ WT,
              float* __restrict__ C, const float* __restrict__ bias)
{
    __shared__ unsigned short As[128 * 64];   // 16 KB
    __shared__ unsigned short Bs[64 * 64];    // 8 KB

    const int tid  = threadIdx.x;
    const int lane = tid & 63;
    const int w    = tid >> 6;
    const int wr   = w >> 1;      // wave row: 64 rows
    const int wc   = w & 1;       // wave col: 32 cols
    const int row_base = blockIdx.y * 128;
    const int col_base = blockIdx.x * 64;

    f32x4 acc[4][2] = {};

    auto stage = [&](int k0) {
#pragma unroll
        for (int r = 0; r < 4; ++r) {
            const int c    = tid + r * 256;
            const int row  = c >> 3;
            const int c7   = c & 7;
            const int goff = ((c7 * 16) ^ ((row & 7) << 4)) >> 1;
            gll16(A + (size_t)(row_base + row) * HDIM + k0 + goff, &As[c * 8]);
        }
#pragma unroll
        for (int r = 0; r < 2; ++r) {
            const int c    = tid + r * 256;
            const int row  = c >> 3;
            const int c7   = c & 7;
            const int goff = ((c7 * 16) ^ ((row & 7) << 4)) >> 1;
            gll16(WT + (size_t)(col_base + row) * HDIM + k0 + goff, &Bs[c * 8]);
        }
    };

    auto compute = [&]() {
#pragma unroll
        for (int kk = 0; kk < 2; ++kk) {
            const int sofs = (kk * 64 + ((lane >> 4) << 4)) ^ ((lane & 7) << 4);
            f16x8 af[4], bfr[2];
#pragma unroll
            for (int mi = 0; mi < 4; ++mi) {
                const int row = wr * 64 + mi * 16 + (lane & 15);
                af[mi] = *reinterpret_cast<const f16x8*>(
                    reinterpret_cast<const char*>(&As[row * 64]) + sofs);
            }
#pragma unroll
            for (int ni = 0; ni < 2; ++ni) {
                const int row = wc * 32 + ni * 16 + (lane & 15);
                bfr[ni] = *reinterpret_cast<const f16x8*>(
                    reinterpret_cast<const char*>(&Bs[row * 64]) + sofs);
            }
#pragma unroll
            for (int mi = 0; mi < 4; ++mi)
#pragma unroll
                for (int ni = 0; ni < 2; ++ni)
                    acc[mi][ni] = __builtin_amdgcn_mfma_f32_16x16x32_f16(
                        af[mi], bfr[ni], acc[mi][ni], 0, 0, 0);
        }
    };

#pragma unroll 1
    for (int kt = 0; kt < 16; ++kt) {
        stage(kt * 64);
        __syncthreads();
        compute();
        __syncthreads();
    }

#pragma unroll
    for (int mi = 0; mi < 4; ++mi) {
#pragma unroll
        for (int ni = 0; ni < 2; ++ni) {
            const int gr0 = row_base + wr * 64 + mi * 16 + ((lane >> 4) << 2);
            const int gc  = col_base + wc * 32 + ni * 16 + (lane & 15);
            const float bv = bias[gc];
#pragma unroll
            for (int r = 0; r < 4; ++r)
                C[(size_t)(gr0 + r) * HDIM + gc] = acc[mi][ni][r] + bv;
        }
    }
}

// ---------------------------------------------------------------------------
// MFMA sparse attention with BLOCK-LEVEL K/V REUSE + counted-vmcnt staging.
// (unchanged from rounds 13-15; ~18 us, not the bottleneck)
// ---------------------------------------------------------------------------
__global__ __launch_bounds__(256)
void attn_mfma(const unsigned short* __restrict__ Qf, const unsigned short* __restrict__ Kf,
               const unsigned short* __restrict__ Kp, const unsigned short* __restrict__ Vt,
               const unsigned short* __restrict__ Vpt,
               unsigned short* __restrict__ Of)
{
    __shared__ unsigned short Ks[2][32 * 64];   // [key][d], swizzled
    __shared__ unsigned short Vs[2][64 * 32];   // [d][jj], swizzled
    __shared__ unsigned short P[4][2][16][40];  // per (wave, qtile) P scratch

    const int tid = threadIdx.x;
    const int L = tid & 63, w = tid >> 6;
    const int c = L & 15, g = L >> 4;
    const int bx = blockIdx.x;
    const int bh = bx & 31;           // bh-minor: XCD ~ bh%8
    const int qb = bx >> 5;           // 16 q-blocks of 128 rows
    const int h  = bh & 15;
    const int b  = bh >> 4;
    const int wr0 = qb * 128 + w * 32;
    const size_t bhs = (size_t)(b * NHEADS + h);

    const unsigned short* __restrict__ Qb  = Qf  + bhs * S_LEN * DHEAD;
    const unsigned short* __restrict__ Kfb = Kf  + bhs * S_LEN * DHEAD;
    const unsigned short* __restrict__ Kpb = Kp  + bhs * NSTRIDED * DHEAD;
    const unsigned short* __restrict__ Vtb = Vt  + bhs * DHEAD * S_LEN;
    const unsigned short* __restrict__ Vpb = Vpt + bhs * DHEAD * NSTRIDED;

    f16x8 qf[2][2];
#pragma unroll
    for (int qi = 0; qi < 2; ++qi) {
        const int row = wr0 + 16 * qi + c;
        qf[qi][0] = *reinterpret_cast<const f16x8*>(&Qb[row * DHEAD + 8 * g]);
        qf[qi][1] = *reinterpret_cast<const f16x8*>(&Qb[row * DHEAD + 32 + 8 * g]);
    }

    f32x4 acc[2][4] = {};
    float m[2]  = {-1e30f, -1e30f};
    float ls[2] = {0.0f, 0.0f};

    auto stage = [&](int bsel, int t) {
        const int jj0 = t * 32;
        {   // Ks: 32 rows x 128B, contiguous in Kp
            const int row  = tid >> 3;
            const int colB = (tid & 7) * 16;
            const int src  = (colB ^ ((row & 7) << 4)) >> 1;
            gll16(Kpb + (jj0 + row) * DHEAD + src, &Ks[bsel][tid * 8]);
        }
        {   // Vs: 64 rows x 64B, rows strided NSTRIDED in Vpt
            const int d    = tid >> 2;
            const int colB = (tid & 3) * 16;
            const int src  = (colB ^ ((d & 3) << 4)) >> 1;
            gll16(Vpb + d * NSTRIDED + jj0 + src, &Vs[bsel][tid * 8]);
        }
    };

    auto softmax_pv = [&](int qi, f32x4 sc0, f32x4 sc1, const f16x8 vfr[4]) {
        float pmax = fmaxf(fmaxf(fmaxf(sc0[0], sc0[1]), fmaxf(sc0[2], sc0[3])),
                           fmaxf(fmaxf(sc1[0], sc1[1]), fmaxf(sc1[2], sc1[3])));
        pmax = fmaxf(pmax, __shfl_xor(pmax, 16));
        pmax = fmaxf(pmax, __shfl_xor(pmax, 32));
        if (__any(pmax > m[qi] + 8.0f)) {       // defer-max
            const float mn = fmaxf(m[qi], pmax);
            const float f  = __expf(m[qi] - mn);
            ls[qi] *= f;
#pragma unroll
            for (int dt = 0; dt < 4; ++dt)
#pragma unroll
                for (int r = 0; r < 4; ++r) acc[qi][dt][r] *= f;
            m[qi] = mn;
        }
        float p[8];
#pragma unroll
        for (int r = 0; r < 4; ++r) p[r]     = __expf(sc0[r] - m[qi]);
#pragma unroll
        for (int r = 0; r < 4; ++r) p[4 + r] = __expf(sc1[r] - m[qi]);
        ls[qi] += ((p[0] + p[1]) + (p[2] + p[3])) + ((p[4] + p[5]) + (p[6] + p[7]));

        char* const Pb = (char*)&P[w][qi][c][0];
        *reinterpret_cast<uint2*>(Pb + 8 * g) =
            make_uint2(pack2_f16(p[0], p[1]), pack2_f16(p[2], p[3]));
        *reinterpret_cast<uint2*>(Pb + 32 + 8 * g) =
            make_uint2(pack2_f16(p[4], p[5]), pack2_f16(p[6], p[7]));
        const f16x8 pf = *reinterpret_cast<const f16x8*>(Pb + 16 * g);

#pragma unroll
        for (int dt = 0; dt < 4; ++dt)
            acc[qi][dt] = __builtin_amdgcn_mfma_f32_16x16x32_f16(
                vfr[dt], pf, acc[qi][dt], 0, 0, 0);
    };

    auto chunk_from_lds = [&](int buf) {
        f16x8 kfr[2][2], vfr[4];
        const char* KsB = (const char*)&Ks[buf][0];
        const char* VsB = (const char*)&Vs[buf][0];
#pragma unroll
        for (int half = 0; half < 2; ++half)
#pragma unroll
            for (int sl = 0; sl < 2; ++sl) {
                const int addr = (half * 16 + c) * 128 +
                                 ((sl * 64 + g * 16) ^ ((c & 7) << 4));
                kfr[half][sl] = *reinterpret_cast<const f16x8*>(KsB + addr);
            }
#pragma unroll
        for (int dt = 0; dt < 4; ++dt) {
            const int d    = dt * 16 + c;
            const int addr = d * 64 + ((g * 16) ^ ((d & 3) << 4));
            vfr[dt] = *reinterpret_cast<const f16x8*>(VsB + addr);
        }
#pragma unroll
        for (int qi = 0; qi < 2; ++qi) {
            f32x4 sc0 = {}, sc1 = {};
            sc0 = __builtin_amdgcn_mfma_f32_16x16x32_f16(kfr[0][0], qf[qi][0], sc0, 0, 0, 0);
            sc0 = __builtin_amdgcn_mfma_f32_16x16x32_f16(kfr[0][1], qf[qi][1], sc0, 0, 0, 0);
            sc1 = __builtin_amdgcn_mfma_f32_16x16x32_f16(kfr[1][0], qf[qi][0], sc1, 0, 0, 0);
            sc1 = __builtin_amdgcn_mfma_f32_16x16x32_f16(kfr[1][1], qf[qi][1], sc1, 0, 0, 0);
            softmax_pv(qi, sc0, sc1, vfr);
        }
    };

    // ---- 16 strided chunks, counted-vmcnt pipeline ----
    stage(0, 0);                       // 2 loads in flight
    int buf = 0;
#pragma unroll 1
    for (int t = 0; t < 15; ++t) {
        stage(buf ^ 1, t + 1);         // 4 in flight
        WAIT_BARRIER(2);
        chunk_from_lds(buf);
        READ_DONE_BARRIER();
        buf ^= 1;
    }
    asm volatile("s_waitcnt vmcnt(0)" ::: "memory");
    __builtin_amdgcn_s_barrier();
    __builtin_amdgcn_sched_barrier(0);
    chunk_from_lds(buf);

    // ---- band chunks: per q-tile, keys j in [wr0+16qi-8, +24), masked ----
#pragma unroll
    for (int qi = 0; qi < 2; ++qi) {
        const int j0 = wr0 + 16 * qi - LOCAL;
        f16x8 kfr[2][2], vfr[4];
#pragma unroll
        for (int half = 0; half < 2; ++half) {
            int j = j0 + half * 16 + c;
            j = min(max(j, 0), S_LEN - 1);
#pragma unroll
            for (int sl = 0; sl < 2; ++sl)
                kfr[half][sl] = *reinterpret_cast<const f16x8*>(
                    &Kfb[j * DHEAD + sl * 32 + 8 * g]);
        }
        int js = j0 + 8 * g;
        js = min(max(js, 0), S_LEN - 8);
#pragma unroll
        for (int dt = 0; dt < 4; ++dt)
            vfr[dt] = *reinterpret_cast<const f16x8*>(
                &Vtb[(dt * 16 + c) * S_LEN + js]);

        f32x4 sc0 = {}, sc1 = {};
        sc0 = __builtin_amdgcn_mfma_f32_16x16x32_f16(kfr[0][0], qf[qi][0], sc0, 0, 0, 0);
        sc0 = __builtin_amdgcn_mfma_f32_16x16x32_f16(kfr[0][1], qf[qi][1], sc0, 0, 0, 0);
        sc1 = __builtin_amdgcn_mfma_f32_16x16x32_f16(kfr[1][0], qf[qi][0], sc1, 0, 0, 0);
        sc1 = __builtin_amdgcn_mfma_f32_16x16x32_f16(kfr[1][1], qf[qi][1], sc1, 0, 0, 0);

        const int i = wr0 + 16 * qi + c;
#pragma unroll
        for (int r = 0; r < 4; ++r) {
            const int j = j0 + 4 * g + r;
            const bool ok = (j >= 0) && (j < S_LEN) && ((j & 3) != 0) &&
                            (j >= i - LOCAL) && (j <= i + LOCAL);
            if (!ok) sc0[r] = -1e30f;
        }
#pragma unroll
        for (int r = 0; r < 4; ++r) {
            const int j = j0 + 16 + 4 * g + r;
            const bool ok = (j >= 0) && (j < S_LEN) && ((j & 3) != 0) &&
                            (j >= i - LOCAL) && (j <= i + LOCAL);
            if (!ok) sc1[r] = -1e30f;
        }
        softmax_pv(qi, sc0, sc1, vfr);
    }

    // ---- finalize ----
#pragma unroll
    for (int qi = 0; qi < 2; ++qi) {
        float lt = ls[qi];
        lt += __shfl_xor(lt, 16);
        lt += __shfl_xor(lt, 32);
        const float inv = 1.0f / lt;
        const int s = wr0 + 16 * qi + c;
        const size_t ob = ((size_t)(b * S_LEN + s)) * HDIM + h * DHEAD;
#pragma unroll
        for (int dt = 0; dt < 4; ++dt) {
            ushort4 hv = make_ushort4(
                f16b(acc[qi][dt][0] * inv), f16b(acc[qi][dt][1] * inv),
                f16b(acc[qi][dt][2] * inv), f16b(acc[qi][dt][3] * inv));
            *reinterpret_cast<ushort4*>(&Of[ob + dt * 16 + 4 * g]) = hv;
        }
    }
}

// ---------------------------------------------------------------------------
// Pipeline: x->fp16, W->fp16 transposed -> QKV fp16 GEMM 128x128 single-buf
// (m97 structure, 3 blocks/CU) -> LDS-reuse MFMA sparse attention -> o-proj
// GEMM 128x64 single-buf (+bias).
// Workspace (52 MB): Xf 0-8 | Wall 8-16 | Qf 16-24 | Kf 24-32 | Kp 32-34 |
//                    Vt 34-42 | Vpt 42-44 | Of 44-52.
// ---------------------------------------------------------------------------
extern "C" void kernel_launch(void* const* d_in, const int* in_sizes, int n_in,
                              void* d_out, int out_size, void* d_ws, size_t ws_size,
                              hipStream_t stream)
{
    const float* x      = (const float*)d_in[0];
    const float* q_w    = (const float*)d_in[1];
    const float* k_w    = (const float*)d_in[2];
    const float* v_w    = (const float*)d_in[3];
    const float* o_w    = (const float*)d_in[4];
    const float* o_b    = (const float*)d_in[5];
    const float* uscale = (const float*)d_in[6];
    float* out = (float*)d_out;

    const size_t MB = (size_t)1 << 20;
    char* ws = (char*)d_ws;
    unsigned short* Xf   = (unsigned short*)(ws);
    unsigned short* Wall = (unsigned short*)(ws + 8 * MB);   // 4 x 2MB fp16 [N][K]
    unsigned short* Qf   = (unsigned short*)(ws + 16 * MB);
    unsigned short* Kf   = (unsigned short*)(ws + 24 * MB);
    unsigned short* Kp   = (unsigned short*)(ws + 32 * MB);
    unsigned short* Vt   = (unsigned short*)(ws + 34 * MB);
    unsigned short* Vpt  = (unsigned short*)(ws + 42 * MB);
    unsigned short* Of   = (unsigned short*)(ws + 44 * MB);

    // prep: x and weights to fp16 (weights transposed)
    xcvt<<<dim3(MROWS * HDIM / 4 / 256), dim3(256), 0, stream>>>(
        x, Xf, MROWS * HDIM / 4);
    wcvt<<<dim3(HDIM / 32, HDIM / 32, 4), dim3(256), 0, stream>>>(
        q_w, k_w, v_w, o_w, Wall);

    // fused QKV projection, 128x128 single-buffered (3 blocks/CU):
    // z in {0,1,2} -> Q / K+Kp / Vt+Vpt
    const dim3 gg(HDIM / 128, MROWS / 128, 3);   // (8, 32, 3) = 768 blocks
    gemm_qkv<<<gg, dim3(256), 0, stream>>>(Xf, Wall, uscale,
                                           Qf, Kf, Kp, Vt, Vpt);

    // LDS-reuse MFMA sparse attention -> Of (fp16 [B,S,H])
    attn_mfma<<<dim3(16 * 32), dim3(256), 0, stream>>>(
        Qf, Kf, Kp, Vt, Vpt, Of);

    // output projection + bias, 128x64 single-buffered (fp32 out)
    const dim3 go(HDIM / 64, MROWS / 128);       // (16, 32) = 512 blocks
    gemm_out<<<go, dim3(256), 0, stream>>>(Of, Wall + 3 * (size_t)HDIM * HDIM,
                                           out, o_b);
}

// Round 17
// 101.105 us; speedup vs baseline: 1.0851x; 1.0851x over previous
//
#include <hip/hip_runtime.h>
#include <math.h>

// Problem constants (fixed by reference)
#define S_LEN   2048
#define HDIM    1024
#define NHEADS  16
#define DHEAD   64
#define BATCH   2
#define MROWS   (BATCH * S_LEN)   // 4096
#define STRIDE  4
#define LOCAL   8
#define NSTRIDED (S_LEN / STRIDE)  // 512

typedef __attribute__((ext_vector_type(8))) _Float16 f16x8;  // 8 fp16 (4 VGPRs)
typedef __attribute__((ext_vector_type(4))) float f32x4;

// ---- fp32 -> fp16 (RN) bit helpers -----------------------------------------
__device__ __forceinline__ unsigned short f16b(float x) {
    _Float16 h = (_Float16)x;
    unsigned short u;
    __builtin_memcpy(&u, &h, 2);
    return u;
}
__device__ __forceinline__ unsigned pack2_f16(float a, float b) {
    return (unsigned)f16b(a) | ((unsigned)f16b(b) << 16);
}

// ---- async global->LDS, 16B per lane (dest = wave base + lane*16) ----------
__device__ __forceinline__ void gll16(const void* g, void* l) {
    __builtin_amdgcn_global_load_lds(
        (const __attribute__((address_space(1))) void*)g,
        (__attribute__((address_space(3))) void*)l, 16, 0, 0);
}

// ---- sync primitives --------------------------------------------------------
#define VMCNT(n)  asm volatile("s_waitcnt vmcnt(" #n ")" ::: "memory")
#define BAR()                                                       \
    do {                                                            \
        __builtin_amdgcn_s_barrier();                               \
        __builtin_amdgcn_sched_barrier(0);                          \
    } while (0)
#define LGKM0()                                                     \
    do {                                                            \
        asm volatile("s_waitcnt lgkmcnt(0)" ::: "memory");          \
        __builtin_amdgcn_sched_barrier(0);                          \
    } while (0)
#define WAIT_BARRIER(N)                                             \
    do { VMCNT(N); BAR(); } while (0)
#define READ_DONE_BARRIER() BAR()

// ---------------------------------------------------------------------------
// Prep 1: x fp32 -> fp16 bits, 4 elems/thread.
// ---------------------------------------------------------------------------
__global__ __launch_bounds__(256)
void xcvt(const float* __restrict__ src, unsigned short* __restrict__ dst, int n4)
{
    const int i = blockIdx.x * 256 + threadIdx.x;
    if (i >= n4) return;
    const float4 v = reinterpret_cast<const float4*>(src)[i];
    reinterpret_cast<ushort4*>(dst)[i] =
        make_ushort4(f16b(v.x), f16b(v.y), f16b(v.z), f16b(v.w));
}

// ---------------------------------------------------------------------------
// Prep 2: weights [K][N] fp32 -> transposed fp16 [N][K]; z picks the weight.
// ---------------------------------------------------------------------------
__global__ __launch_bounds__(256)
void wcvt(const float* __restrict__ W0, const float* __restrict__ W1,
          const float* __restrict__ W2, const float* __restrict__ W3,
          unsigned short* __restrict__ dst)
{
    __shared__ unsigned short tile[32][33];
    const int z = blockIdx.z;
    const float* __restrict__ W = (z == 0) ? W0 : (z == 1) ? W1 : (z == 2) ? W2 : W3;
    unsigned short* __restrict__ out = dst + (size_t)z * HDIM * HDIM;
    const int t  = threadIdx.x;
    const int kb = blockIdx.x * 32;
    const int nb = blockIdx.y * 32;
    {
        const int row = t >> 3;
        const int c4  = (t & 7) * 4;
        const float4 v = *reinterpret_cast<const float4*>(
            &W[(size_t)(kb + row) * HDIM + nb + c4]);
        tile[row][c4 + 0] = f16b(v.x);
        tile[row][c4 + 1] = f16b(v.y);
        tile[row][c4 + 2] = f16b(v.z);
        tile[row][c4 + 3] = f16b(v.w);
    }
    __syncthreads();
    {
        const int n  = t >> 3;
        const int k4 = (t & 7) * 4;
        *reinterpret_cast<ushort4*>(&out[(size_t)(nb + n) * HDIM + kb + k4]) =
            make_ushort4(tile[k4][n], tile[k4+1][n], tile[k4+2][n], tile[k4+3][n]);
    }
}

// ---------------------------------------------------------------------------
// QKV fp16 MFMA GEMM — 8-PHASE SCHEDULE (T3+T4+T5), 256x256 tile, 512 thr
// (8 waves 2Mx4N, wave tile 128x64), BK=64, 16 iters x 4 phases.
// Per phase: {4-8 ds_read_b128 subtile ∥ 2 gll prefetch ∥ vmcnt(2)@p0,p1 ->
// barrier -> lgkmcnt(0) -> setprio(1) 16 MFMA setprio(0)}. Counted vmcnt:
// prefetch order B0 B1 B2 B3 A0 A2 A1 A3 makes vmcnt(2) exact (in-order
// retirement, m135); loads span phases -- never drained in the main loop.
// LDS 128 KB double-buffered; linear dest + pre-swizzled source (proven,
// 0 bank conflicts). Grid (4,16,3) = 192 blocks.
// Epilogue (z): 0 -> Q scaled; 1 -> K + Kp; 2 -> Vt + Vpt.
// ---------------------------------------------------------------------------
__global__ __launch_bounds__(512)
void gemm_qkv(const unsigned short* __restrict__ A,
              const unsigned short* __restrict__ Wbase,
              const float* __restrict__ sig_ptr,
              unsigned short* __restrict__ Qf, unsigned short* __restrict__ Kf,
              unsigned short* __restrict__ Kp, unsigned short* __restrict__ Vt,
              unsigned short* __restrict__ Vpt)
{
    __shared__ unsigned short As[2][256 * 64];   // 64 KB
    __shared__ unsigned short Bs[2][256 * 64];   // 64 KB

    const int z = blockIdx.z;
    const unsigned short* __restrict__ WT = Wbase + (size_t)z * HDIM * HDIM;

    const int tid  = threadIdx.x;
    const int lane = tid & 63;
    const int w    = tid >> 6;    // 0..7
    const int wr   = w >> 2;      // 0..1 : 128-row half
    const int wc   = w & 3;       // 0..3 : 64-col quarter
    const int row_base = blockIdx.y * 256;
    const int col_base = blockIdx.x * 256;

    f32x4 acc[8][4] = {};         // 128 VGPRs
    f16x8 bf[4];                  // B frags for current kk
    f16x8 af[4];                  // A frags for current phase

    // one 16B chunk per call; chunk id = tid + r*512, row = c>>3 (0..255)
    auto stageA = [&](int b, int k0, int r) {
        const int c    = tid + r * 512;
        const int row  = c >> 3;
        const int c7   = c & 7;
        const int goff = ((c7 * 16) ^ ((row & 7) << 4)) >> 1;
        gll16(A + (size_t)(row_base + row) * HDIM + k0 + goff, &As[b][c * 8]);
    };
    auto stageB = [&](int b, int k0, int r) {
        const int c    = tid + r * 512;
        const int row  = c >> 3;
        const int c7   = c & 7;
        const int goff = ((c7 * 16) ^ ((row & 7) << 4)) >> 1;
        gll16(WT + (size_t)(col_base + row) * HDIM + k0 + goff, &Bs[b][c * 8]);
    };

    auto ldA = [&](int b, int mi, int kk) -> f16x8 {
        const int row  = wr * 128 + mi * 16 + (lane & 15);
        const int sofs = (kk * 64 + ((lane >> 4) << 4)) ^ ((lane & 7) << 4);
        return *reinterpret_cast<const f16x8*>(
            reinterpret_cast<const char*>(&As[b][row * 64]) + sofs);
    };
    auto ldB = [&](int b, int ni, int kk) -> f16x8 {
        const int row  = wc * 64 + ni * 16 + (lane & 15);
        const int sofs = (kk * 64 + ((lane >> 4) << 4)) ^ ((lane & 7) << 4);
        return *reinterpret_cast<const f16x8*>(
            reinterpret_cast<const char*>(&Bs[b][row * 64]) + sofs);
    };

    auto mfma4x4 = [&](int mibase) {
        __builtin_amdgcn_s_setprio(1);
#pragma unroll
        for (int mi = 0; mi < 4; ++mi)
#pragma unroll
            for (int ni = 0; ni < 4; ++ni)
                acc[mibase + mi][ni] = __builtin_amdgcn_mfma_f32_16x16x32_f16(
                    af[mi], bf[ni], acc[mibase + mi][ni], 0, 0, 0);
        __builtin_amdgcn_s_setprio(0);
    };

    // ---- prologue: fill buffer 0 in dependency order (B all, A H0, A H1) ----
    stageB(0, 0, 0); stageB(0, 0, 1); stageB(0, 0, 2); stageB(0, 0, 3);
    stageA(0, 0, 0); stageA(0, 0, 2); stageA(0, 0, 1); stageA(0, 0, 3);

    // ---- main loop: iters 0..14, 4 phases each ----
#pragma unroll 1
    for (int kt = 0; kt < 15; ++kt) {
        const int b   = kt & 1;
        const int nb  = b ^ 1;
        const int nk0 = (kt + 1) * 64;

        // phase 0: kk=0, mi 0..3 (+ B kk0).  Needs B-all + A-H0 (prev p2);
        // outstanding = prev p3's 2 -> vmcnt(2).
        WAIT_BARRIER(2);
#pragma unroll
        for (int mi = 0; mi < 4; ++mi) af[mi] = ldA(b, mi, 0);
#pragma unroll
        for (int ni = 0; ni < 4; ++ni) bf[ni] = ldB(b, ni, 0);
        stageB(nb, nk0, 0); stageB(nb, nk0, 1);
        LGKM0();
        mfma4x4(0);

        // phase 1: kk=0, mi 4..7.  Needs A-H1 (prev p3, oldest 2 of 4) -> vmcnt(2).
        WAIT_BARRIER(2);
#pragma unroll
        for (int mi = 0; mi < 4; ++mi) af[mi] = ldA(b, 4 + mi, 0);
        stageB(nb, nk0, 2); stageB(nb, nk0, 3);
        LGKM0();
        mfma4x4(4);

        // phase 2: kk=1, mi 0..3 (+ B kk1).  Regions already certified.
        BAR();
#pragma unroll
        for (int mi = 0; mi < 4; ++mi) af[mi] = ldA(b, mi, 1);
#pragma unroll
        for (int ni = 0; ni < 4; ++ni) bf[ni] = ldB(b, ni, 1);
        stageA(nb, nk0, 0); stageA(nb, nk0, 2);
        LGKM0();
        mfma4x4(0);

        // phase 3: kk=1, mi 4..7.
        BAR();
#pragma unroll
        for (int mi = 0; mi < 4; ++mi) af[mi] = ldA(b, 4 + mi, 1);
        stageA(nb, nk0, 1); stageA(nb, nk0, 3);
        LGKM0();
        mfma4x4(4);
    }

    // ---- peeled last iter (kt=15, buffer 1, no prefetch) ----
    {
        const int b = 1;
        WAIT_BARRIER(2);                   // B-all + A-H0 (prev p3 outstanding)
#pragma unroll
        for (int mi = 0; mi < 4; ++mi) af[mi] = ldA(b, mi, 0);
#pragma unroll
        for (int ni = 0; ni < 4; ++ni) bf[ni] = ldB(b, ni, 0);
        LGKM0();
        mfma4x4(0);

        WAIT_BARRIER(0);                   // A-H1: no newer issues -> drain
#pragma unroll
        for (int mi = 0; mi < 4; ++mi) af[mi] = ldA(b, 4 + mi, 0);
        LGKM0();
        mfma4x4(4);

        BAR();
#pragma unroll
        for (int mi = 0; mi < 4; ++mi) af[mi] = ldA(b, mi, 1);
#pragma unroll
        for (int ni = 0; ni < 4; ++ni) bf[ni] = ldB(b, ni, 1);
        LGKM0();
        mfma4x4(0);

        BAR();
#pragma unroll
        for (int mi = 0; mi < 4; ++mi) af[mi] = ldA(b, 4 + mi, 1);
        LGKM0();
        mfma4x4(4);
    }

    // ---- attention-layout epilogue ----
    float scale = 1.0f;
    if (z == 0) {
        const float u = *sig_ptr;
        scale = (1.0f / (1.0f + __expf(-u))) * 0.125f;  // sigmoid(phi)/sqrt(D)
    }
#pragma unroll
    for (int mi = 0; mi < 8; ++mi) {
#pragma unroll
        for (int ni = 0; ni < 4; ++ni) {
            const int gr0 = row_base + wr * 128 + mi * 16 + ((lane >> 4) << 2);
            const int gc  = col_base + wc * 64 + ni * 16 + (lane & 15);
            const int h = gc >> 6, d = gc & 63;
            const int bb = gr0 >> 11;
            const int s0 = gr0 & (S_LEN - 1);       // multiple of 4
            const size_t bh = (size_t)(bb * NHEADS + h);
            if (z == 0) {
#pragma unroll
                for (int r = 0; r < 4; ++r)
                    Qf[(bh * S_LEN + s0 + r) * DHEAD + d] =
                        f16b(acc[mi][ni][r] * scale);
            } else if (z == 1) {
#pragma unroll
                for (int r = 0; r < 4; ++r)
                    Kf[(bh * S_LEN + s0 + r) * DHEAD + d] = f16b(acc[mi][ni][r]);
                Kp[(bh * NSTRIDED + (s0 >> 2)) * DHEAD + d] = f16b(acc[mi][ni][0]);
            } else {
                ushort4 pv = make_ushort4(f16b(acc[mi][ni][0]), f16b(acc[mi][ni][1]),
                                          f16b(acc[mi][ni][2]), f16b(acc[mi][ni][3]));
                *reinterpret_cast<ushort4*>(&Vt[(bh * DHEAD + d) * S_LEN + s0]) = pv;
                Vpt[(bh * DHEAD + d) * NSTRIDED + (s0 >> 2)] = pv.x;
            }
        }
    }
}

// ---------------------------------------------------------------------------
// O-projection fp16 MFMA GEMM, 128(M)x64(N) tile, SINGLE-buffered 24 KB LDS,
// plain 2-barrier loop. Grid (16,32) = 512 blocks.  (unchanged, round 16)
// ---------------------------------------------------------------------------
__global__ __launch_bounds__(256)
void gemm_out(const unsigned short* __restrict__ A,
              const unsigned short* __restrict__ WT,
              float* __restrict__ C, const float* __restrict__ bias)
{
    __shared__ unsigned short As[128 * 64];   // 16 KB
    __shared__ unsigned short Bs[64 * 64];    // 8 KB

    const int tid  = threadIdx.x;
    const int lane = tid & 63;
    const int w    = tid >> 6;
    const int wr   = w >> 1;      // wave row: 64 rows
    const int wc   = w & 1;       // wave col: 32 cols
    const int row_base = blockIdx.y * 128;
    const int col_base = blockIdx.x * 64;

    f32x4 acc[4][2] = {};

    auto stage = [&](int k0) {
#pragma unroll
        for (int r = 0; r < 4; ++r) {
            const int c    = tid + r * 256;
            const int row  = c >> 3;
            const int c7   = c & 7;
            const int goff = ((c7 * 16) ^ ((row & 7) << 4)) >> 1;
            gll16(A + (size_t)(row_base + row) * HDIM + k0 + goff, &As[c * 8]);
        }
#pragma unroll
        for (int r = 0; r < 2; ++r) {
            const int c    = tid + r * 256;
            const int row  = c >> 3;
            const int c7   = c & 7;
            const int goff = ((c7 * 16) ^ ((row & 7) << 4)) >> 1;
            gll16(WT + (size_t)(col_base + row) * HDIM + k0 + goff, &Bs[c * 8]);
        }
    };

    auto compute = [&]() {
#pragma unroll
        for (int kk = 0; kk < 2; ++kk) {
            const int sofs = (kk * 64 + ((lane >> 4) << 4)) ^ ((lane & 7) << 4);
            f16x8 af[4], bfr[2];
#pragma unroll
            for (int mi = 0; mi < 4; ++mi) {
                const int row = wr * 64 + mi * 16 + (lane & 15);
                af[mi] = *reinterpret_cast<const f16x8*>(
                    reinterpret_cast<const char*>(&As[row * 64]) + sofs);
            }
#pragma unroll
            for (int ni = 0; ni < 2; ++ni) {
                const int row = wc * 32 + ni * 16 + (lane & 15);
                bfr[ni] = *reinterpret_cast<const f16x8*>(
                    reinterpret_cast<const char*>(&Bs[row * 64]) + sofs);
            }
#pragma unroll
            for (int mi = 0; mi < 4; ++mi)
#pragma unroll
                for (int ni = 0; ni < 2; ++ni)
                    acc[mi][ni] = __builtin_amdgcn_mfma_f32_16x16x32_f16(
                        af[mi], bfr[ni], acc[mi][ni], 0, 0, 0);
        }
    };

#pragma unroll 1
    for (int kt = 0; kt < 16; ++kt) {
        stage(kt * 64);
        __syncthreads();
        compute();
        __syncthreads();
    }

#pragma unroll
    for (int mi = 0; mi < 4; ++mi) {
#pragma unroll
        for (int ni = 0; ni < 2; ++ni) {
            const int gr0 = row_base + wr * 64 + mi * 16 + ((lane >> 4) << 2);
            const int gc  = col_base + wc * 32 + ni * 16 + (lane & 15);
            const float bv = bias[gc];
#pragma unroll
            for (int r = 0; r < 4; ++r)
                C[(size_t)(gr0 + r) * HDIM + gc] = acc[mi][ni][r] + bv;
        }
    }
}

// ---------------------------------------------------------------------------
// MFMA sparse attention with BLOCK-LEVEL K/V REUSE + counted-vmcnt staging.
// (unchanged from rounds 13-16; ~18 us, not the bottleneck)
// ---------------------------------------------------------------------------
__global__ __launch_bounds__(256)
void attn_mfma(const unsigned short* __restrict__ Qf, const unsigned short* __restrict__ Kf,
               const unsigned short* __restrict__ Kp, const unsigned short* __restrict__ Vt,
               const unsigned short* __restrict__ Vpt,
               unsigned short* __restrict__ Of)
{
    __shared__ unsigned short Ks[2][32 * 64];   // [key][d], swizzled
    __shared__ unsigned short Vs[2][64 * 32];   // [d][jj], swizzled
    __shared__ unsigned short P[4][2][16][40];  // per (wave, qtile) P scratch

    const int tid = threadIdx.x;
    const int L = tid & 63, w = tid >> 6;
    const int c = L & 15, g = L >> 4;
    const int bx = blockIdx.x;
    const int bh = bx & 31;           // bh-minor: XCD ~ bh%8
    const int qb = bx >> 5;           // 16 q-blocks of 128 rows
    const int h  = bh & 15;
    const int b  = bh >> 4;
    const int wr0 = qb * 128 + w * 32;
    const size_t bhs = (size_t)(b * NHEADS + h);

    const unsigned short* __restrict__ Qb  = Qf  + bhs * S_LEN * DHEAD;
    const unsigned short* __restrict__ Kfb = Kf  + bhs * S_LEN * DHEAD;
    const unsigned short* __restrict__ Kpb = Kp  + bhs * NSTRIDED * DHEAD;
    const unsigned short* __restrict__ Vtb = Vt  + bhs * DHEAD * S_LEN;
    const unsigned short* __restrict__ Vpb = Vpt + bhs * DHEAD * NSTRIDED;

    f16x8 qf[2][2];
#pragma unroll
    for (int qi = 0; qi < 2; ++qi) {
        const int row = wr0 + 16 * qi + c;
        qf[qi][0] = *reinterpret_cast<const f16x8*>(&Qb[row * DHEAD + 8 * g]);
        qf[qi][1] = *reinterpret_cast<const f16x8*>(&Qb[row * DHEAD + 32 + 8 * g]);
    }

    f32x4 acc[2][4] = {};
    float m[2]  = {-1e30f, -1e30f};
    float ls[2] = {0.0f, 0.0f};

    auto stage = [&](int bsel, int t) {
        const int jj0 = t * 32;
        {   // Ks: 32 rows x 128B, contiguous in Kp
            const int row  = tid >> 3;
            const int colB = (tid & 7) * 16;
            const int src  = (colB ^ ((row & 7) << 4)) >> 1;
            gll16(Kpb + (jj0 + row) * DHEAD + src, &Ks[bsel][tid * 8]);
        }
        {   // Vs: 64 rows x 64B, rows strided NSTRIDED in Vpt
            const int d    = tid >> 2;
            const int colB = (tid & 3) * 16;
            const int src  = (colB ^ ((d & 3) << 4)) >> 1;
            gll16(Vpb + d * NSTRIDED + jj0 + src, &Vs[bsel][tid * 8]);
        }
    };

    auto softmax_pv = [&](int qi, f32x4 sc0, f32x4 sc1, const f16x8 vfr[4]) {
        float pmax = fmaxf(fmaxf(fmaxf(sc0[0], sc0[1]), fmaxf(sc0[2], sc0[3])),
                           fmaxf(fmaxf(sc1[0], sc1[1]), fmaxf(sc1[2], sc1[3])));
        pmax = fmaxf(pmax, __shfl_xor(pmax, 16));
        pmax = fmaxf(pmax, __shfl_xor(pmax, 32));
        if (__any(pmax > m[qi] + 8.0f)) {       // defer-max
            const float mn = fmaxf(m[qi], pmax);
            const float f  = __expf(m[qi] - mn);
            ls[qi] *= f;
#pragma unroll
            for (int dt = 0; dt < 4; ++dt)
#pragma unroll
                for (int r = 0; r < 4; ++r) acc[qi][dt][r] *= f;
            m[qi] = mn;
        }
        float p[8];
#pragma unroll
        for (int r = 0; r < 4; ++r) p[r]     = __expf(sc0[r] - m[qi]);
#pragma unroll
        for (int r = 0; r < 4; ++r) p[4 + r] = __expf(sc1[r] - m[qi]);
        ls[qi] += ((p[0] + p[1]) + (p[2] + p[3])) + ((p[4] + p[5]) + (p[6] + p[7]));

        char* const Pb = (char*)&P[w][qi][c][0];
        *reinterpret_cast<uint2*>(Pb + 8 * g) =
            make_uint2(pack2_f16(p[0], p[1]), pack2_f16(p[2], p[3]));
        *reinterpret_cast<uint2*>(Pb + 32 + 8 * g) =
            make_uint2(pack2_f16(p[4], p[5]), pack2_f16(p[6], p[7]));
        const f16x8 pf = *reinterpret_cast<const f16x8*>(Pb + 16 * g);

#pragma unroll
        for (int dt = 0; dt < 4; ++dt)
            acc[qi][dt] = __builtin_amdgcn_mfma_f32_16x16x32_f16(
                vfr[dt], pf, acc[qi][dt], 0, 0, 0);
    };

    auto chunk_from_lds = [&](int buf) {
        f16x8 kfr[2][2], vfr[4];
        const char* KsB = (const char*)&Ks[buf][0];
        const char* VsB = (const char*)&Vs[buf][0];
#pragma unroll
        for (int half = 0; half < 2; ++half)
#pragma unroll
            for (int sl = 0; sl < 2; ++sl) {
                const int addr = (half * 16 + c) * 128 +
                                 ((sl * 64 + g * 16) ^ ((c & 7) << 4));
                kfr[half][sl] = *reinterpret_cast<const f16x8*>(KsB + addr);
            }
#pragma unroll
        for (int dt = 0; dt < 4; ++dt) {
            const int d    = dt * 16 + c;
            const int addr = d * 64 + ((g * 16) ^ ((d & 3) << 4));
            vfr[dt] = *reinterpret_cast<const f16x8*>(VsB + addr);
        }
#pragma unroll
        for (int qi = 0; qi < 2; ++qi) {
            f32x4 sc0 = {}, sc1 = {};
            sc0 = __builtin_amdgcn_mfma_f32_16x16x32_f16(kfr[0][0], qf[qi][0], sc0, 0, 0, 0);
            sc0 = __builtin_amdgcn_mfma_f32_16x16x32_f16(kfr[0][1], qf[qi][1], sc0, 0, 0, 0);
            sc1 = __builtin_amdgcn_mfma_f32_16x16x32_f16(kfr[1][0], qf[qi][0], sc1, 0, 0, 0);
            sc1 = __builtin_amdgcn_mfma_f32_16x16x32_f16(kfr[1][1], qf[qi][1], sc1, 0, 0, 0);
            softmax_pv(qi, sc0, sc1, vfr);
        }
    };

    // ---- 16 strided chunks, counted-vmcnt pipeline ----
    stage(0, 0);                       // 2 loads in flight
    int buf = 0;
#pragma unroll 1
    for (int t = 0; t < 15; ++t) {
        stage(buf ^ 1, t + 1);         // 4 in flight
        WAIT_BARRIER(2);
        chunk_from_lds(buf);
        READ_DONE_BARRIER();
        buf ^= 1;
    }
    VMCNT(0);
    BAR();
    chunk_from_lds(buf);

    // ---- band chunks: per q-tile, keys j in [wr0+16qi-8, +24), masked ----
#pragma unroll
    for (int qi = 0; qi < 2; ++qi) {
        const int j0 = wr0 + 16 * qi - LOCAL;
        f16x8 kfr[2][2], vfr[4];
#pragma unroll
        for (int half = 0; half < 2; ++half) {
            int j = j0 + half * 16 + c;
            j = min(max(j, 0), S_LEN - 1);
#pragma unroll
            for (int sl = 0; sl < 2; ++sl)
                kfr[half][sl] = *reinterpret_cast<const f16x8*>(
                    &Kfb[j * DHEAD + sl * 32 + 8 * g]);
        }
        int js = j0 + 8 * g;
        js = min(max(js, 0), S_LEN - 8);
#pragma unroll
        for (int dt = 0; dt < 4; ++dt)
            vfr[dt] = *reinterpret_cast<const f16x8*>(
                &Vtb[(dt * 16 + c) * S_LEN + js]);

        f32x4 sc0 = {}, sc1 = {};
        sc0 = __builtin_amdgcn_mfma_f32_16x16x32_f16(kfr[0][0], qf[qi][0], sc0, 0, 0, 0);
        sc0 = __builtin_amdgcn_mfma_f32_16x16x32_f16(kfr[0][1], qf[qi][1], sc0, 0, 0, 0);
        sc1 = __builtin_amdgcn_mfma_f32_16x16x32_f16(kfr[1][0], qf[qi][0], sc1, 0, 0, 0);
        sc1 = __builtin_amdgcn_mfma_f32_16x16x32_f16(kfr[1][1], qf[qi][1], sc1, 0, 0, 0);

        const int i = wr0 + 16 * qi + c;
#pragma unroll
        for (int r = 0; r < 4; ++r) {
            const int j = j0 + 4 * g + r;
            const bool ok = (j >= 0) && (j < S_LEN) && ((j & 3) != 0) &&
                            (j >= i - LOCAL) && (j <= i + LOCAL);
            if (!ok) sc0[r] = -1e30f;
        }
#pragma unroll
        for (int r = 0; r < 4; ++r) {
            const int j = j0 + 16 + 4 * g + r;
            const bool ok = (j >= 0) && (j < S_LEN) && ((j & 3) != 0) &&
                            (j >= i - LOCAL) && (j <= i + LOCAL);
            if (!ok) sc1[r] = -1e30f;
        }
        softmax_pv(qi, sc0, sc1, vfr);
    }

    // ---- finalize ----
#pragma unroll
    for (int qi = 0; qi < 2; ++qi) {
        float lt = ls[qi];
        lt += __shfl_xor(lt, 16);
        lt += __shfl_xor(lt, 32);
        const float inv = 1.0f / lt;
        const int s = wr0 + 16 * qi + c;
        const size_t ob = ((size_t)(b * S_LEN + s)) * HDIM + h * DHEAD;
#pragma unroll
        for (int dt = 0; dt < 4; ++dt) {
            ushort4 hv = make_ushort4(
                f16b(acc[qi][dt][0] * inv), f16b(acc[qi][dt][1] * inv),
                f16b(acc[qi][dt][2] * inv), f16b(acc[qi][dt][3] * inv));
            *reinterpret_cast<ushort4*>(&Of[ob + dt * 16 + 4 * g]) = hv;
        }
    }
}

// ---------------------------------------------------------------------------
// Pipeline: x->fp16, W->fp16 transposed -> QKV fp16 GEMM 256x256 8-PHASE
// (attention layouts) -> LDS-reuse MFMA sparse attention -> o-proj GEMM
// 128x64 single-buf (+bias).
// Workspace (52 MB): Xf 0-8 | Wall 8-16 | Qf 16-24 | Kf 24-32 | Kp 32-34 |
//                    Vt 34-42 | Vpt 42-44 | Of 44-52.
// ---------------------------------------------------------------------------
extern "C" void kernel_launch(void* const* d_in, const int* in_sizes, int n_in,
                              void* d_out, int out_size, void* d_ws, size_t ws_size,
                              hipStream_t stream)
{
    const float* x      = (const float*)d_in[0];
    const float* q_w    = (const float*)d_in[1];
    const float* k_w    = (const float*)d_in[2];
    const float* v_w    = (const float*)d_in[3];
    const float* o_w    = (const float*)d_in[4];
    const float* o_b    = (const float*)d_in[5];
    const float* uscale = (const float*)d_in[6];
    float* out = (float*)d_out;

    const size_t MB = (size_t)1 << 20;
    char* ws = (char*)d_ws;
    unsigned short* Xf   = (unsigned short*)(ws);
    unsigned short* Wall = (unsigned short*)(ws + 8 * MB);   // 4 x 2MB fp16 [N][K]
    unsigned short* Qf   = (unsigned short*)(ws + 16 * MB);
    unsigned short* Kf   = (unsigned short*)(ws + 24 * MB);
    unsigned short* Kp   = (unsigned short*)(ws + 32 * MB);
    unsigned short* Vt   = (unsigned short*)(ws + 34 * MB);
    unsigned short* Vpt  = (unsigned short*)(ws + 42 * MB);
    unsigned short* Of   = (unsigned short*)(ws + 44 * MB);

    // prep: x and weights to fp16 (weights transposed)
    xcvt<<<dim3(MROWS * HDIM / 4 / 256), dim3(256), 0, stream>>>(
        x, Xf, MROWS * HDIM / 4);
    wcvt<<<dim3(HDIM / 32, HDIM / 32, 4), dim3(256), 0, stream>>>(
        q_w, k_w, v_w, o_w, Wall);

    // fused QKV projection, 256x256 8-phase, 512 threads:
    // z in {0,1,2} -> Q / K+Kp / Vt+Vpt
    const dim3 gg(HDIM / 256, MROWS / 256, 3);   // (4, 16, 3) = 192 blocks
    gemm_qkv<<<gg, dim3(512), 0, stream>>>(Xf, Wall, uscale,
                                           Qf, Kf, Kp, Vt, Vpt);

    // LDS-reuse MFMA sparse attention -> Of (fp16 [B,S,H])
    attn_mfma<<<dim3(16 * 32), dim3(256), 0, stream>>>(
        Qf, Kf, Kp, Vt, Vpt, Of);

    // output projection + bias, 128x64 single-buffered (fp32 out)
    const dim3 go(HDIM / 64, MROWS / 128);       // (16, 32) = 512 blocks
    gemm_out<<<go, dim3(256), 0, stream>>>(Of, Wall + 3 * (size_t)HDIM * HDIM,
                                           out, o_b);
}